// Round 13
// baseline (183.802 us; speedup 1.0000x reference)
//
#include <hip/hip_runtime.h>

// out[n][p][m] = sum_c x[n][c][p] * rm[n][c][m]
// N=16, C=64, P=65536, M=128. Memory-bound: 256MB read + 512MB write -> floor ~122us.
// v13 = v4 structure at PT=256 via 512-thread blocks: staging wave-instrs read
//      1KB contiguous per c-row (vs v4's 512B) -- tests the HBM read-burst /
//      DRAM-page-granularity theory, the only one consistent with v2..v12
//      (v2=v4=v10=161.5 across different internals; drains/LDS/occupancy all
//      falsified; v12's 256B bursts were worse). A-frags direct from global
//      (validated), bf16 LDS [c][264] single buffer 33KB, 2 barriers/tile,
//      lgkm-only waits, 2 blocks/CU = 16 waves/CU (same concurrency as v4).

#define NB   16
#define CDIM 64
#define PDIM 65536
#define MDIM 128
#define PT   256
#define BLOCKS_PER_N 32
#define TILES 8           // (PDIM/PT)/BLOCKS_PER_N
#define XS   264          // lds_x row stride (bf16), +8 pad (v4's +4 scaled)

typedef __attribute__((ext_vector_type(8))) short bf16x8;
typedef __attribute__((ext_vector_type(4))) float f32x4;

__device__ __forceinline__ unsigned short f2bf(float f) {
  union { float f; unsigned int u; } v; v.f = f;
  unsigned int u = v.u;
  u += 0x7fffu + ((u >> 16) & 1u);  // RNE
  return (unsigned short)(u >> 16);
}

// pack two fp32 -> two bf16 (RNE) in one u32 (lo = first element)
__device__ __forceinline__ unsigned int pack2bf(float flo, float fhi) {
  union { float f; unsigned int u; } a, b;
  a.f = flo; b.f = fhi;
  unsigned int ua = a.u + (0x7fffu + ((a.u >> 16) & 1u));
  unsigned int ub = b.u + (0x7fffu + ((b.u >> 16) & 1u));
  return (ua >> 16) | (ub & 0xffff0000u);
}

union pk8 { bf16x8 f; unsigned int u[4]; };

// x tile: [c][p], p XOR-swizzled by c-group (v4-verified pattern).
// XOR touches only p bits 4-5, so 4-elem (8B) write chunks stay contiguous.
__device__ __forceinline__ int xswz(int c, int p) {
  return c * XS + (p ^ (((c >> 3) & 3) << 4));
}

__global__ __launch_bounds__(512, 4) void nlsa_kernel(
    const float* __restrict__ x, const float* __restrict__ rm,
    float* __restrict__ out) {
  __shared__ unsigned short lds_x[CDIM * XS];   // 33KB -> 2 blocks/CU

  const int t = threadIdx.x;
  const int b = blockIdx.x;
  const int n  = b >> 5;           // 32 blocks per n
  const int bt = b & 31;

  const float* xn   = x  + (size_t)n * CDIM * PDIM;
  const float* rmn  = rm + (size_t)n * CDIM * MDIM;
  float*       outn = out + (size_t)n * PDIM * MDIM;

  // x staging map: thread t loads float4 at (c = cst+8*it, p = pst..pst+3).
  // Per wave-instr: ONE c-row x 64 lanes x 16B = 1KB contiguous global.
  const int cst = t >> 6;          // 0..7 (= wave id)
  const int pst = (t & 63) * 4;    // 0..252

  float4 r[8];
  {
    const float* src = xn + (size_t)(bt * PT + pst);
#pragma unroll
    for (int it = 0; it < 8; ++it)
      r[it] = *(const float4*)(src + (size_t)(cst + it * 8) * PDIM);
  }

  const int w_ = t >> 6;    // wave 0..7
  const int mh = w_ & 3;    // m-quarter: m range [32mh, 32mh+32)
  const int ph = w_ >> 2;   // p-half: p offset 128*ph
  const int l  = t & 63;
  const int lo = l & 15;
  const int g  = l >> 4;

  // ---- A fragments (rm) straight from global, once (validated v8/v9/v11/v12).
  // A[m][c]: m = mh*32 + mt*16 + lo, c = ks*32 + g*8 + i.
  bf16x8 a[2][2];
  {
    const float* rs = rmn + (size_t)(g * 8) * MDIM + mh * 32 + lo;
#pragma unroll
    for (int mt = 0; mt < 2; ++mt)
#pragma unroll
      for (int ks = 0; ks < 2; ++ks) {
        float v[8];
#pragma unroll
        for (int i = 0; i < 8; ++i)
          v[i] = rs[(size_t)(ks * 32 + i) * MDIM + mt * 16];
        pk8 p;
#pragma unroll
        for (int j = 0; j < 4; ++j) p.u[j] = pack2bf(v[2 * j], v[2 * j + 1]);
        a[mt][ks] = p.f;
      }
  }

  for (int k = 0; k < TILES; ++k) {
    // barrier1: all waves done reading lds_x for tile k-1 (reads consumed
    // pre-barrier) -- raw barrier, no vm/store drain.
    asm volatile("" ::: "memory");
    __builtin_amdgcn_s_barrier();
    asm volatile("" ::: "memory");

    // write staged tile into lds_x (compiler inserts counted vmcnt for r)
#pragma unroll
    for (int it = 0; it < 8; ++it) {
      ushort4 v;
      v.x = f2bf(r[it].x); v.y = f2bf(r[it].y);
      v.z = f2bf(r[it].z); v.w = f2bf(r[it].w);
      *(ushort4*)&lds_x[xswz(cst + it * 8, pst)] = v;
    }

    // prefetch tile k+1 into r (overlaps the compute phase below)
    if (k + 1 < TILES) {
      const float* src = xn + (size_t)((bt + (k + 1) * BLOCKS_PER_N) * PT + pst);
#pragma unroll
      for (int it = 0; it < 8; ++it)
        r[it] = *(const float4*)(src + (size_t)(cst + it * 8) * PDIM);
    }

    // barrier2: lds_x writes visible; lgkm-only wait (store queue NOT drained)
    asm volatile("s_waitcnt lgkmcnt(0)" ::: "memory");
    __builtin_amdgcn_s_barrier();
    asm volatile("" ::: "memory");

    const int p_base = (bt + k * BLOCKS_PER_N) * PT;
#pragma unroll
    for (int pt_ = 0; pt_ < 8; ++pt_) {
      const int pl  = ph * 128 + pt_ * 16 + lo;
      const int pls = pl ^ (g << 4);   // matches xswz for c-groups g and g+4
      bf16x8 b0, b1;
#pragma unroll
      for (int i = 0; i < 8; ++i) {
        b0[i] = (short)lds_x[(g * 8 + i) * XS + pls];
        b1[i] = (short)lds_x[(32 + g * 8 + i) * XS + pls];
      }
      f32x4 acc0 = {0.f, 0.f, 0.f, 0.f};
      f32x4 acc1 = {0.f, 0.f, 0.f, 0.f};
      acc0 = __builtin_amdgcn_mfma_f32_16x16x32_bf16(a[0][0], b0, acc0, 0, 0, 0);
      acc0 = __builtin_amdgcn_mfma_f32_16x16x32_bf16(a[0][1], b1, acc0, 0, 0, 0);
      acc1 = __builtin_amdgcn_mfma_f32_16x16x32_bf16(a[1][0], b0, acc1, 0, 0, 0);
      acc1 = __builtin_amdgcn_mfma_f32_16x16x32_bf16(a[1][1], b1, acc1, 0, 0, 0);

      float* dst = outn + (size_t)(p_base + pl) * MDIM + mh * 32 + g * 4;
      *(f32x4*)(dst)      = acc0;   // m = 32mh + 4g + {0..3}
      *(f32x4*)(dst + 16) = acc1;   // m = 32mh + 16 + 4g + {0..3}
    }
  }
}

extern "C" void kernel_launch(void* const* d_in, const int* in_sizes, int n_in,
                              void* d_out, int out_size, void* d_ws, size_t ws_size,
                              hipStream_t stream) {
  const float* x  = (const float*)d_in[0];   // (N, C, H, W) fp32
  const float* rm = (const float*)d_in[1];   // (N, C, M) fp32
  float* out = (float*)d_out;                // (N, P, M) fp32
  nlsa_kernel<<<dim3(NB * BLOCKS_PER_N), dim3(512), 0, stream>>>(x, rm, out);
}

// Round 14
// 161.969 us; speedup vs baseline: 1.1348x; 1.1348x over previous
//
#include <hip/hip_runtime.h>

// out[n][p][m] = sum_c x[n][c][p] * rm[n][c][m]
// N=16, C=64, P=65536, M=128. Memory-bound: 256MB read + 512MB write.
// FINAL = v10 (best measured: 161.4us, 4.77 TB/s effective on 768MB).
// Structure: PT=128 tiles, 256-thread blocks, 4 blocks/CU; fp32->bf16 at
// staging; [p][c] MFMA-native LDS with slot-XOR swizzle (1 ds_read_b128 per
// fragment); 2 raw barriers/tile with lgkm-only waits (no store-queue drain);
// 1-deep register prefetch; coalesced float4 reads (512B/c-row bursts).
// Measured plateau evidence: v2/v4/v10 (three different internal structures)
// all converge at 161.5us; 256B bursts (v12) and 1KB bursts (v13) both worse;
// occupancy beyond 16 waves/CU unreachable at this LDS/VGPR shape; drains,
// bank conflicts, LDS op mix, nt-stores all measured cost-free or negative.
// Mixed-stream model: 512MB@6.6 + 256MB@~3.2 (512B strided strips) ~= 158us.

#define NB   16
#define CDIM 64
#define PDIM 65536
#define MDIM 128
#define PT   128
#define BLOCKS_PER_N 64
#define TILES_PER_BLOCK 8

typedef __attribute__((ext_vector_type(8))) short bf16x8;
typedef __attribute__((ext_vector_type(4))) float f32x4;

__device__ __forceinline__ unsigned short f2bf(float f) {
  union { float f; unsigned int u; } v; v.f = f;
  unsigned int u = v.u;
  u += 0x7fffu + ((u >> 16) & 1u);  // RNE
  return (unsigned short)(u >> 16);
}

// pack two fp32 -> two bf16 (RNE) in one u32 (lo = first)
__device__ __forceinline__ unsigned int pack2bf(float flo, float fhi) {
  union { float f; unsigned int u; } a, b;
  a.f = flo; b.f = fhi;
  unsigned int ua = a.u + (0x7fffu + ((a.u >> 16) & 1u));
  unsigned int ub = b.u + (0x7fffu + ((b.u >> 16) & 1u));
  return (ua >> 16) | (ub & 0xffff0000u);
}

// rm tile swizzle (verified v1-v10): [m][64c] bf16, 16B-slot XOR
__device__ __forceinline__ int swz(int row, int col) {
  int slot = (col >> 3) ^ (row & 7);
  return row * 64 + slot * 8 + (col & 7);
}

__global__ __launch_bounds__(256, 4) void nlsa_kernel(
    const float* __restrict__ x, const float* __restrict__ rm,
    float* __restrict__ out) {
  __shared__ unsigned short lds_rm[MDIM * CDIM];  // 16KB
  __shared__ unsigned short lds_xT[PT * CDIM];    // [p][c] bf16, 16KB

  const int t = threadIdx.x;
  const int b = blockIdx.x;
  const int n  = b >> 6;
  const int bt = b & 63;

  const float* xn   = x  + (size_t)n * CDIM * PDIM;
  const float* rmn  = rm + (size_t)n * CDIM * MDIM;
  float*       outn = out + (size_t)n * PDIM * MDIM;

  // x staging map: thread t loads float4 at (c = C8+it, p = P4..P4+3), it=0..7.
  const int C8 = (t >> 5) * 8;     // 0,8,..,56
  const int P4 = (t & 31) * 4;     // 0..124

  float4 r[8];
  {
    const float* src = xn + (size_t)(bt * PT + P4);
#pragma unroll
    for (int it = 0; it < 8; ++it)
      r[it] = *(const float4*)(src + (size_t)(C8 + it) * PDIM);
  }

  // ---- stage rm[n] -> lds_rm[m][c] bf16 (once per block)
  {
    const int m  = t & 127;
    const int cb = (t >> 7) * 4;
#pragma unroll
    for (int it = 0; it < 8; ++it) {
      const int c0 = cb + it * 8;
      ushort4 v;
      v.x = f2bf(rmn[(c0 + 0) * MDIM + m]);
      v.y = f2bf(rmn[(c0 + 1) * MDIM + m]);
      v.z = f2bf(rmn[(c0 + 2) * MDIM + m]);
      v.w = f2bf(rmn[(c0 + 3) * MDIM + m]);
      *(ushort4*)&lds_rm[swz(m, c0)] = v;
    }
  }
  __syncthreads();

  const int w_ = t >> 6;    // wave: m range [32w_, 32w_+32)
  const int l  = t & 63;
  const int lo = l & 15;
  const int g  = l >> 4;

  // A fragments (rm) in registers for the whole kernel
  bf16x8 a[2][2];
#pragma unroll
  for (int mt = 0; mt < 2; ++mt)
#pragma unroll
    for (int ks = 0; ks < 2; ++ks)
      a[mt][ks] = *(const bf16x8*)&lds_rm[swz(w_ * 32 + mt * 16 + lo,
                                              ks * 32 + g * 8)];

  // write one [p][c] row (16B = 8 consecutive c) with slot-XOR swizzle
#define PACKROW(dp, comp)                                                    \
  {                                                                          \
    unsigned int q0 = pack2bf(r[0].comp, r[1].comp);                         \
    unsigned int q1 = pack2bf(r[2].comp, r[3].comp);                         \
    unsigned int q2 = pack2bf(r[4].comp, r[5].comp);                         \
    unsigned int q3 = pack2bf(r[6].comp, r[7].comp);                         \
    const int p_ = P4 + dp;                                                  \
    const int slot_ = (t >> 5) ^ ((p_ >> 1) & 7);                            \
    uint4 qq; qq.x = q0; qq.y = q1; qq.z = q2; qq.w = q3;                    \
    *(uint4*)&lds_xT[p_ * 64 + slot_ * 8] = qq;                              \
  }

  for (int k = 0; k < TILES_PER_BLOCK; ++k) {
    // barrier1: all waves done reading lds_xT for tile k-1 (reads consumed
    // pre-barrier) -- raw barrier, no vm/store drain.
    asm volatile("" ::: "memory");
    __builtin_amdgcn_s_barrier();
    asm volatile("" ::: "memory");

    // transpose-pack tile k into lds_xT[p][c] (counted vmcnt for r auto)
    PACKROW(0, x)
    PACKROW(1, y)
    PACKROW(2, z)
    PACKROW(3, w)

    // prefetch tile k+1 into r (overlaps the compute phase below)
    if (k + 1 < TILES_PER_BLOCK) {
      const float* src = xn + (size_t)((bt + (k + 1) * BLOCKS_PER_N) * PT + P4);
#pragma unroll
      for (int it = 0; it < 8; ++it)
        r[it] = *(const float4*)(src + (size_t)(C8 + it) * PDIM);
    }

    // barrier2: lds writes visible; lgkm-only wait (store queue NOT drained)
    asm volatile("s_waitcnt lgkmcnt(0)" ::: "memory");
    __builtin_amdgcn_s_barrier();
    asm volatile("" ::: "memory");

    const int p_base = (bt + k * BLOCKS_PER_N) * PT;
#pragma unroll
    for (int pt_ = 0; pt_ < 8; ++pt_) {
      const int prow = pt_ * 16 + lo;
      const int sx   = (prow >> 1) & 7;
      // one b128 per fragment: c = g*8..g*8+7 (b0), 32+g*8.. (b1) at p = prow
      bf16x8 b0 = *(const bf16x8*)&lds_xT[prow * 64 + ((g ^ sx)) * 8];
      bf16x8 b1 = *(const bf16x8*)&lds_xT[prow * 64 + (((4 + g) ^ sx)) * 8];

      f32x4 acc0 = {0.f, 0.f, 0.f, 0.f};
      f32x4 acc1 = {0.f, 0.f, 0.f, 0.f};
      acc0 = __builtin_amdgcn_mfma_f32_16x16x32_bf16(a[0][0], b0, acc0, 0, 0, 0);
      acc0 = __builtin_amdgcn_mfma_f32_16x16x32_bf16(a[0][1], b1, acc0, 0, 0, 0);
      acc1 = __builtin_amdgcn_mfma_f32_16x16x32_bf16(a[1][0], b0, acc1, 0, 0, 0);
      acc1 = __builtin_amdgcn_mfma_f32_16x16x32_bf16(a[1][1], b1, acc1, 0, 0, 0);

      float* dst = outn + (size_t)(p_base + prow) * MDIM + w_ * 32 + g * 4;
      *(f32x4*)(dst)      = acc0;   // m = 32w_ + 4g + {0..3}
      *(f32x4*)(dst + 16) = acc1;   // m = 32w_ + 16 + 4g + {0..3}
    }
  }
#undef PACKROW
}

extern "C" void kernel_launch(void* const* d_in, const int* in_sizes, int n_in,
                              void* d_out, int out_size, void* d_ws, size_t ws_size,
                              hipStream_t stream) {
  const float* x  = (const float*)d_in[0];   // (N, C, H, W) fp32
  const float* rm = (const float*)d_in[1];   // (N, C, M) fp32
  float* out = (float*)d_out;                // (N, P, M) fp32
  nlsa_kernel<<<dim3(NB * BLOCKS_PER_N), dim3(256), 0, stream>>>(x, rm, out);
}